// Round 4
// baseline (127.503 us; speedup 1.0000x reference)
//
#include <hip/hip_runtime.h>
#include <float.h>

// VQ-VAE vector quantizer forward, MI355X — bf16 MFMA with exact 3-way split.
// x: [B=32, C=64, H=64, W=64] fp32; emb: [K=512, D=64] fp32.
// out flat (b, h*w, c): out[g*64 + c] = emb[argmin_k ||x_g - emb_k||^2][c].
//
// R11: intra-wave software pipeline. R10 (4 waves/SIMD) proved occupancy
// isn't the lever (61->55.5us only): per kt the wave serializes
// load -> vmcnt wait (~200cy L2) -> 24 MFMA -> tail, and in-phase waves
// alternate load-bursts with MFMA-bursts (pipe 45% busy). R11 ping-pongs
// two B-fragment register buffers (kt unrolled x2, no copies): loads for
// kt+1 issue BEFORE the MFMA cluster on kt and are consumed AFTER it, so
// the counted vmcnt lands behind ~470cy of MFMA work (T3/T4 pattern).
// s_setprio(1) wraps each MFMA cluster (T5; waves are barrier-free ->
// role diversity). kt0 loads issue before the split3 prologue. +48 regs
// -> __launch_bounds__(256,3). Numerics bit-identical to R7/R9/R10.
// MFMA floor 24.8us; prediction 34-40us at MfmaUtil 55-65%.
//
// Verified layouts (m89/m91/m120): A[m=lane&15][k=quad*8+j],
// B[n=lane&15][k=quad*8+j], D col=lane&15, row=quad*4+reg.

typedef __attribute__((ext_vector_type(8))) short  short8;
typedef __attribute__((ext_vector_type(4))) float  floatx4;

#define HWD 4096
#define CD  64
#define KD  512
#define PT  128    // positions per block
#define KT  128    // emb rows staged per nt (fallback path)
#define ESR 72     // fallback LDS row stride in bf16 elems

// ws layout: bs = 32 kt-tiles x 3072 ushorts ([lvl][ch][lane][8]) = 196608 B,
// + one kt tile (6144 B) of prefetch pad; then esq_p = 1024 floats
// + 32 floats of prefetch pad (last ping-pong prefetch reads tile 32).
#define KT_USH    3072
#define BS_BYTES  (32 * KT_USH * 2)
#define ESQ_OFF   (BS_BYTES + KT_USH * 2)                 // 202752
#define WS_NEEDED (ESQ_OFF + 1056 * (int)sizeof(float))   // 206976

// round-to-nearest-even fp32 -> bf16 (bit-level; inputs are finite)
__device__ inline unsigned short bf16_rne(float v) {
    unsigned int u = __builtin_bit_cast(unsigned int, v);
    u += 0x7fffu + ((u >> 16) & 1u);
    return (unsigned short)(u >> 16);
}
__device__ inline float bf16_val(unsigned short h) {
    return __builtin_bit_cast(float, (unsigned int)h << 16);
}
// exact 3-way split: v = h + m + l + eps, |eps| <= 2^-27 |v|
__device__ inline void split3(float v, unsigned short& h, unsigned short& m,
                              unsigned short& l) {
    h = bf16_rne(v);
    float r1 = v - bf16_val(h);     // exact in fp32
    m = bf16_rne(r1);
    float r2 = r1 - bf16_val(m);    // exact in fp32
    l = bf16_rne(r2);
}

#define MFMA(A, B, C) __builtin_amdgcn_mfma_f32_16x16x32_bf16((A), (B), (C), 0, 0, 0)

// ---- prep: split emb into B-fragment layout + |e|^2 half-row partials ----
// thread t (0..1023): k = t>>1, half = t&1. Same load order / fmaf chain /
// split3 as R7's in-block staging -> bit-identical values.
__global__ void vq_prep(const float* __restrict__ emb,
                        unsigned short* __restrict__ bs,
                        float* __restrict__ esq_p) {
    const int t    = blockIdx.x * blockDim.x + threadIdx.x;  // 0..1023
    const int k    = t >> 1;
    const int half = t & 1;
    const int kt   = k >> 4;
    const int n16  = k & 15;
    const float* eg = emb + (size_t)k * CD + half * 32;
    // base of this (kt, ch=half, n16) within bs, ushort units
    unsigned short* bb = bs + (size_t)kt * KT_USH + half * 512 + n16 * 8;
    float s = 0.f;
    #pragma unroll
    for (int q = 0; q < 8; ++q) {
        float4 ev = *(const float4*)(eg + q * 4);
        float vv[4] = {ev.x, ev.y, ev.z, ev.w};
        #pragma unroll
        for (int i = 0; i < 4; ++i) {
            s = fmaf(vv[i], vv[i], s);
            unsigned short h, m, l;
            split3(vv[i], h, m, l);
            const int c    = half * 32 + q * 4 + i;   // 0..63
            const int quad = (c >> 3) & 3;
            const int j    = c & 7;
            const int off  = quad * 128 + j;          // (quad*16)*8 + j
            bb[off]        = h;                       // lvl 0
            bb[1024 + off] = m;                       // lvl 1
            bb[2048 + off] = l;                       // lvl 2
        }
    }
    esq_p[2 * k + half] = s;
}

// ---- main kernel: ping-pong B prefetch, setprio'd MFMA clusters ----
__launch_bounds__(256, 3)
__global__ void vq_mfma_kernel(const float* __restrict__ x,
                               const unsigned short* __restrict__ bs,
                               const float* __restrict__ esq_p,
                               const float* __restrict__ emb,
                               float* __restrict__ out) {
    const int tid  = threadIdx.x;
    const int lane = tid & 63;
    const int wv   = __builtin_amdgcn_readfirstlane(tid >> 6);  // 0..3
    const int n16  = lane & 15;   // m for A, n for B, col for D
    const int quad = lane >> 4;   // k-quad for A/B, row-quad for D

    const int g0 = blockIdx.x << 7;   // 128 positions per block
    const int b  = g0 >> 12;          // 128 | 4096: no b straddle
    const int n0 = g0 & 4095;

    __shared__ int bk_s[PT];

    // ---- issue kt0 B-fragment + |e|^2 loads first: their L2 latency
    //      hides under the split3 prologue's long VALU phase ----
    const short8* bpp = (const short8*)bs + lane;
    short8 f[6], g[6];
    #pragma unroll
    for (int i = 0; i < 6; ++i) f[i] = bpp[i * 64];
    float2 eqf2 = *(const float2*)&esq_p[2 * n16];

    // ---- A fragments: load x, split to 3 bf16 frags (held whole kernel) ----
    // pos = g0 + wv*32 + mt*16 + n16 ; k(c) = ch*32 + quad*8 + j
    short8 ah[2][2], am[2][2], al[2][2];
    {
        const float* xb = x + (size_t)b * (CD * HWD) + n0 + wv * 32 + n16;
        #pragma unroll
        for (int mt = 0; mt < 2; ++mt)
            #pragma unroll
            for (int ch = 0; ch < 2; ++ch) {
                #pragma unroll
                for (int j = 0; j < 8; ++j) {
                    float v = xb[(size_t)(ch * 32 + quad * 8 + j) * HWD + mt * 16];
                    unsigned short h, m, l;
                    split3(v, h, m, l);
                    ah[mt][ch][j] = (short)h;
                    am[mt][ch][j] = (short)m;
                    al[mt][ch][j] = (short)l;
                }
            }
    }

    float bestd[8]; int bestk[8];
    #pragma unroll
    for (int i = 0; i < 8; ++i) { bestd[i] = FLT_MAX; bestk[i] = 0; }

    // 6-class small->large accumulation; mt-inner gives 2-way MFMA ILP.
    // F[0],F[1]=e_h  F[2],F[3]=e_m  F[4],F[5]=e_l  (ch 0/1 each)
    #define CLUSTER(F, ACC)                                                   \
        { __builtin_amdgcn_s_setprio(1);                                      \
          _Pragma("unroll")                                                   \
          for (int mt = 0; mt < 2; ++mt) ACC[mt] = MFMA(al[mt][0], F[0], ACC[mt]); \
          _Pragma("unroll")                                                   \
          for (int mt = 0; mt < 2; ++mt) ACC[mt] = MFMA(al[mt][1], F[1], ACC[mt]); \
          _Pragma("unroll")                                                   \
          for (int mt = 0; mt < 2; ++mt) ACC[mt] = MFMA(am[mt][0], F[2], ACC[mt]); \
          _Pragma("unroll")                                                   \
          for (int mt = 0; mt < 2; ++mt) ACC[mt] = MFMA(am[mt][1], F[3], ACC[mt]); \
          _Pragma("unroll")                                                   \
          for (int mt = 0; mt < 2; ++mt) ACC[mt] = MFMA(ah[mt][0], F[4], ACC[mt]); \
          _Pragma("unroll")                                                   \
          for (int mt = 0; mt < 2; ++mt) ACC[mt] = MFMA(ah[mt][1], F[5], ACC[mt]); \
          _Pragma("unroll")                                                   \
          for (int mt = 0; mt < 2; ++mt) ACC[mt] = MFMA(am[mt][0], F[0], ACC[mt]); \
          _Pragma("unroll")                                                   \
          for (int mt = 0; mt < 2; ++mt) ACC[mt] = MFMA(am[mt][1], F[1], ACC[mt]); \
          _Pragma("unroll")                                                   \
          for (int mt = 0; mt < 2; ++mt) ACC[mt] = MFMA(ah[mt][0], F[2], ACC[mt]); \
          _Pragma("unroll")                                                   \
          for (int mt = 0; mt < 2; ++mt) ACC[mt] = MFMA(ah[mt][1], F[3], ACC[mt]); \
          _Pragma("unroll")                                                   \
          for (int mt = 0; mt < 2; ++mt) ACC[mt] = MFMA(ah[mt][0], F[0], ACC[mt]); \
          _Pragma("unroll")                                                   \
          for (int mt = 0; mt < 2; ++mt) ACC[mt] = MFMA(ah[mt][1], F[1], ACC[mt]); \
          __builtin_amdgcn_s_setprio(0); }

    // distances + running argmin (k ascending: strict < keeps lowest k)
    #define TAIL(ACC, EQ2, KV)                                                \
        { const float eq_ = (EQ2).x + (EQ2).y;                                \
          _Pragma("unroll")                                                   \
          for (int mt = 0; mt < 2; ++mt)                                      \
              _Pragma("unroll")                                               \
              for (int r = 0; r < 4; ++r) {                                   \
                  float d = fmaf(-2.f, ACC[mt][r], eq_);                      \
                  int idx = mt * 4 + r;                                       \
                  if (d < bestd[idx]) { bestd[idx] = d; bestk[idx] = (KV); }  \
              } }

    // ---- main loop: 16 iterations x 2 kt, ping-pong f/g ----
    #pragma unroll 1
    for (int it = 0; it < 16; ++it) {
        // even kt = 2it: prefetch kt+1 into g, compute on f
        #pragma unroll
        for (int i = 0; i < 6; ++i) g[i] = bpp[384 + i * 64];
        float2 eqg2 = *(const float2*)&esq_p[2 * (it * 32 + 16 + n16)];
        floatx4 accf[2];
        #pragma unroll
        for (int mt = 0; mt < 2; ++mt) accf[mt] = (floatx4){0.f, 0.f, 0.f, 0.f};
        CLUSTER(f, accf)
        TAIL(accf, eqf2, it * 32 + n16)

        // odd kt = 2it+1: prefetch kt+2 into f, compute on g
        // (it=15 prefetches tile 32 / esq rows 512+ -> dedicated ws pads)
        #pragma unroll
        for (int i = 0; i < 6; ++i) f[i] = bpp[768 + i * 64];
        eqf2 = *(const float2*)&esq_p[2 * (it * 32 + 32 + n16)];
        floatx4 accg[2];
        #pragma unroll
        for (int mt = 0; mt < 2; ++mt) accg[mt] = (floatx4){0.f, 0.f, 0.f, 0.f};
        CLUSTER(g, accg)
        TAIL(accg, eqg2, it * 32 + 16 + n16)

        bpp += 768;
    }
    #undef CLUSTER
    #undef TAIL

    // ---- cross-lane argmin over the 16 code-columns (lane bits 0..3) ----
    #pragma unroll
    for (int msk = 1; msk <= 8; msk <<= 1)
        #pragma unroll
        for (int i = 0; i < 8; ++i) {
            float od = __shfl_xor(bestd[i], msk, 64);
            int   ok = __shfl_xor(bestk[i], msk, 64);
            bool take = (od < bestd[i]) || (od == bestd[i] && ok < bestk[i]);
            if (take) { bestd[i] = od; bestk[i] = ok; }
        }
    // D row = quad*4 + r within tile -> pos = wv*32 + mt*16 + quad*4 + r
    if (n16 == 0) {
        #pragma unroll
        for (int mt = 0; mt < 2; ++mt)
            #pragma unroll
            for (int r = 0; r < 4; ++r)
                bk_s[wv * 32 + mt * 16 + quad * 4 + r] = bestk[mt * 4 + r];
    }
    __syncthreads();

    // ---- gather epilogue: wave-uniform rows, 256-B coalesced, batched ----
    const size_t ob = (size_t)g0 * CD;
    for (int it = 0; it < 8; ++it) {
        float v[4]; int pp[4];
        #pragma unroll
        for (int j = 0; j < 4; ++j) {
            int p = (it * 4 + j) * 4 + wv;
            pp[j] = p;
            v[j]  = emb[bk_s[p] * CD + lane];   // L2-hot fp32 row
        }
        #pragma unroll
        for (int j = 0; j < 4; ++j)
            out[ob + (size_t)pp[j] * CD + lane] = v[j];
    }
}

// ---- fallback (no workspace): verbatim R7 kernel, 123.7 us known-good ----
__launch_bounds__(256, 2)
__global__ void vq_mfma_fb(const float* __restrict__ x,
                           const float* __restrict__ emb,
                           float* __restrict__ out) {
    const int tid  = threadIdx.x;
    const int lane = tid & 63;
    const int wv   = __builtin_amdgcn_readfirstlane(tid >> 6);  // 0..3
    const int n16  = lane & 15;
    const int quad = lane >> 4;

    const int g0 = blockIdx.x << 8;
    const int b  = g0 >> 12;
    const int n0 = g0 & 4095;

    __shared__ unsigned short es_h[KT][ESR];
    __shared__ unsigned short es_m[KT][ESR];
    __shared__ unsigned short es_l[KT][ESR];
    __shared__ float esq_p[2 * KT];
    __shared__ int   bk_s[256];

    short8 ah[4][2], am[4][2], al[4][2];
    {
        const float* xb = x + (size_t)b * (CD * HWD) + n0 + wv * 64 + n16;
        #pragma unroll
        for (int mt = 0; mt < 4; ++mt)
            #pragma unroll
            for (int ch = 0; ch < 2; ++ch) {
                #pragma unroll
                for (int j = 0; j < 8; ++j) {
                    float v = xb[(size_t)(ch * 32 + quad * 8 + j) * HWD + mt * 16];
                    unsigned short h, m, l;
                    split3(v, h, m, l);
                    ah[mt][ch][j] = (short)h;
                    am[mt][ch][j] = (short)m;
                    al[mt][ch][j] = (short)l;
                }
            }
    }

    float bestd[16]; int bestk[16];
    #pragma unroll
    for (int i = 0; i < 16; ++i) { bestd[i] = FLT_MAX; bestk[i] = 0; }

    const int lr   = tid >> 1;
    const int half = tid & 1;

    for (int nt = 0; nt < KD / KT; ++nt) {
        __syncthreads();
        {
            const float* eg = emb + (size_t)(nt * KT + lr) * CD + half * 32;
            float s = 0.f;
            #pragma unroll
            for (int q = 0; q < 8; ++q) {
                float4 ev = *(const float4*)(eg + q * 4);
                float vv[4] = {ev.x, ev.y, ev.z, ev.w};
                ushort4 h4, m4, l4;
                unsigned short* hp = (unsigned short*)&h4;
                unsigned short* mp = (unsigned short*)&m4;
                unsigned short* lp = (unsigned short*)&l4;
                #pragma unroll
                for (int i = 0; i < 4; ++i) {
                    s = fmaf(vv[i], vv[i], s);
                    split3(vv[i], hp[i], mp[i], lp[i]);
                }
                int c0 = half * 32 + q * 4;
                *(ushort4*)&es_h[lr][c0] = h4;
                *(ushort4*)&es_m[lr][c0] = m4;
                *(ushort4*)&es_l[lr][c0] = l4;
            }
            esq_p[2 * lr + half] = s;
        }
        __syncthreads();

        #pragma unroll 2
        for (int ln = 0; ln < 8; ++ln) {
            const int krow = ln * 16 + n16;
            const unsigned short* ph = &es_h[krow][quad * 8];
            const unsigned short* pm = &es_m[krow][quad * 8];
            const unsigned short* pl = &es_l[krow][quad * 8];
            short8 bh0 = *(const short8*)ph,  bh1 = *(const short8*)(ph + 32);
            short8 bm0 = *(const short8*)pm,  bm1 = *(const short8*)(pm + 32);
            short8 bl0 = *(const short8*)pl,  bl1 = *(const short8*)(pl + 32);
            const float eq = esq_p[2 * krow] + esq_p[2 * krow + 1];
            const int   kv = nt * KT + ln * 16 + n16;

            floatx4 acc[4];
            #pragma unroll
            for (int mt = 0; mt < 4; ++mt) acc[mt] = (floatx4){0.f, 0.f, 0.f, 0.f};

            #define STEPF(AR, B0, B1)                                         \
                { _Pragma("unroll")                                           \
                  for (int mt = 0; mt < 4; ++mt) acc[mt] = MFMA(AR[mt][0], B0, acc[mt]); \
                  _Pragma("unroll")                                           \
                  for (int mt = 0; mt < 4; ++mt) acc[mt] = MFMA(AR[mt][1], B1, acc[mt]); }
            STEPF(al, bh0, bh1)
            STEPF(am, bm0, bm1)
            STEPF(ah, bl0, bl1)
            STEPF(am, bh0, bh1)
            STEPF(ah, bm0, bm1)
            STEPF(ah, bh0, bh1)
            #undef STEPF

            #pragma unroll
            for (int mt = 0; mt < 4; ++mt)
                #pragma unroll
                for (int r = 0; r < 4; ++r) {
                    float d = fmaf(-2.f, acc[mt][r], eq);
                    int idx = mt * 4 + r;
                    if (d < bestd[idx]) { bestd[idx] = d; bestk[idx] = kv; }
                }
        }
    }

    #pragma unroll
    for (int msk = 1; msk <= 8; msk <<= 1)
        #pragma unroll
        for (int i = 0; i < 16; ++i) {
            float od = __shfl_xor(bestd[i], msk, 64);
            int   ok = __shfl_xor(bestk[i], msk, 64);
            bool take = (od < bestd[i]) || (od == bestd[i] && ok < bestk[i]);
            if (take) { bestd[i] = od; bestk[i] = ok; }
        }
    if (n16 == 0) {
        #pragma unroll
        for (int mt = 0; mt < 4; ++mt)
            #pragma unroll
            for (int r = 0; r < 4; ++r)
                bk_s[wv * 64 + mt * 16 + quad * 4 + r] = bestk[mt * 4 + r];
    }
    __syncthreads();

    const size_t ob = (size_t)g0 * CD;
    for (int it = 0; it < 16; ++it) {
        float v[4]; int pp[4];
        #pragma unroll
        for (int j = 0; j < 4; ++j) {
            int p = (it * 4 + j) * 4 + wv;
            pp[j] = p;
            v[j]  = emb[bk_s[p] * CD + lane];
        }
        #pragma unroll
        for (int j = 0; j < 4; ++j)
            out[ob + (size_t)pp[j] * CD + lane] = v[j];
    }
}

extern "C" void kernel_launch(void* const* d_in, const int* in_sizes, int n_in,
                              void* d_out, int out_size, void* d_ws, size_t ws_size,
                              hipStream_t stream) {
    const float* x   = (const float*)d_in[0];   // 32*64*64*64
    const float* emb = (const float*)d_in[1];   // 512*64
    float* out = (float*)d_out;                 // 8388608 floats

    if (d_ws != nullptr && ws_size >= (size_t)WS_NEEDED) {
        unsigned short* bs = (unsigned short*)d_ws;       // 196608 B + 6 KB pad
        float* esq_p = (float*)((char*)d_ws + ESQ_OFF);   // 1024 + 32 pad floats
        vq_prep<<<16, 64, 0, stream>>>(emb, bs, esq_p);
        vq_mfma_kernel<<<1024, 256, 0, stream>>>(x, bs, esq_p, emb, out);
    } else {
        vq_mfma_fb<<<512, 256, 0, stream>>>(x, emb, out);
    }
}

// Round 5
// 123.475 us; speedup vs baseline: 1.0326x; 1.0326x over previous
//
#include <hip/hip_runtime.h>
#include <float.h>

// VQ-VAE vector quantizer forward, MI355X — bf16 MFMA with exact 3-way split.
// x: [B=32, C=64, H=64, W=64] fp32; emb: [K=512, D=64] fp32.
// out flat (b, h*w, c): out[g*64 + c] = emb[argmin_k ||x_g - emb_k||^2][c].
//
// R12: B-fragments through LDS, staged once per BLOCK via global_load_lds.
// R10/R11 analysis: per kt-round each CU moved 104 KB of (identical) B
// fragments through the L1 port (~1700 cy) against 1864 cy of matrix work,
// and the two phases serialized -> all variants stuck at 55-61 us with
// MfmaUtil ~35-45%. R12 stages the 6 KB tile into LDS once per block
// (global traffic /4), double-buffered, async global_load_lds width=16
// (chunk c of the tile IS fragment c: linear lane*16 layout), 1 barrier
// per kt; staged loads complete under the MFMA cluster so the barrier
// drain is cheap. ds_read_b128 at lane*16 is bank-conflict-free.
// Prep kernel now pre-sums |e|^2 (same half0+half1 order -> bit-identical).
// 4 blocks/CU (launch_bounds(256,4)); no setprio (barrier-lockstep).
// Numerics bit-identical to R7/R9/R10/R11. MFMA floor 24.8 us;
// prediction ~30-36 us at MfmaUtil 55-70%.
//
// Verified layouts (m89/m91/m120): A[m=lane&15][k=quad*8+j],
// B[n=lane&15][k=quad*8+j], D col=lane&15, row=quad*4+reg.

typedef __attribute__((ext_vector_type(8))) short  short8;
typedef __attribute__((ext_vector_type(4))) float  floatx4;

#define HWD 4096
#define CD  64
#define KD  512
#define PT  128    // positions per block
#define KT  128    // emb rows staged per nt (fallback path)
#define ESR 72     // fallback LDS row stride in bf16 elems

// ws layout: bs = 32 kt-tiles x 3072 ushorts ([lvl][ch][lane][8]) = 196608 B,
// + one kt tile (6144 B) of prefetch pad; then esq = 512 floats (pre-summed
// |e|^2 per code) + 32 floats of prefetch pad.
#define KT_USH    3072
#define TILE_B    (KT_USH * 2)                            // 6144 B per tile
#define BS_BYTES  (32 * TILE_B)
#define ESQ_OFF   (BS_BYTES + TILE_B)                     // 202752
#define WS_NEEDED (ESQ_OFF + 544 * (int)sizeof(float))    // 204928

// round-to-nearest-even fp32 -> bf16 (bit-level; inputs are finite)
__device__ inline unsigned short bf16_rne(float v) {
    unsigned int u = __builtin_bit_cast(unsigned int, v);
    u += 0x7fffu + ((u >> 16) & 1u);
    return (unsigned short)(u >> 16);
}
__device__ inline float bf16_val(unsigned short h) {
    return __builtin_bit_cast(float, (unsigned int)h << 16);
}
// exact 3-way split: v = h + m + l + eps, |eps| <= 2^-27 |v|
__device__ inline void split3(float v, unsigned short& h, unsigned short& m,
                              unsigned short& l) {
    h = bf16_rne(v);
    float r1 = v - bf16_val(h);     // exact in fp32
    m = bf16_rne(r1);
    float r2 = r1 - bf16_val(m);    // exact in fp32
    l = bf16_rne(r2);
}

#define MFMA(A, B, C) __builtin_amdgcn_mfma_f32_16x16x32_bf16((A), (B), (C), 0, 0, 0)

// async global -> LDS, 16 B per lane; LDS dest is wave-uniform base + lane*16
__device__ inline void gload_lds16(const void* g, void* l) {
    __builtin_amdgcn_global_load_lds(
        (const __attribute__((address_space(1))) void*)g,
        (__attribute__((address_space(3))) void*)l, 16, 0, 0);
}

// ---- prep: split emb into B-fragment layout + pre-summed |e|^2 ----
// thread t (0..1023): k = t>>1, half = t&1. Same load order / fmaf chain /
// split3 as R7's staging; eq = half0_partial + half1_partial (same order)
// -> bit-identical distances.
__global__ void vq_prep(const float* __restrict__ emb,
                        unsigned short* __restrict__ bs,
                        float* __restrict__ esq) {
    const int t    = blockIdx.x * blockDim.x + threadIdx.x;  // 0..1023
    const int k    = t >> 1;
    const int half = t & 1;
    const int kt   = k >> 4;
    const int n16  = k & 15;
    const float* eg = emb + (size_t)k * CD + half * 32;
    // base of this (kt, ch=half, n16) within bs, ushort units
    unsigned short* bb = bs + (size_t)kt * KT_USH + half * 512 + n16 * 8;
    float s = 0.f;
    #pragma unroll
    for (int q = 0; q < 8; ++q) {
        float4 ev = *(const float4*)(eg + q * 4);
        float vv[4] = {ev.x, ev.y, ev.z, ev.w};
        #pragma unroll
        for (int i = 0; i < 4; ++i) {
            s = fmaf(vv[i], vv[i], s);
            unsigned short h, m, l;
            split3(vv[i], h, m, l);
            const int c    = half * 32 + q * 4 + i;   // 0..63
            const int quad = (c >> 3) & 3;
            const int j    = c & 7;
            const int off  = quad * 128 + j;          // (quad*16)*8 + j
            bb[off]        = h;                       // lvl 0
            bb[1024 + off] = m;                       // lvl 1
            bb[2048 + off] = l;                       // lvl 2
        }
    }
    // lanes 2k, 2k+1 hold the two half-partials of code k
    float o = __shfl_xor(s, 1, 64);
    if (half == 0) esq[k] = s + o;    // == R7's esq_p[2k] + esq_p[2k+1]
}

// ---- main kernel: LDS-staged B tiles, double-buffered, 1 barrier/kt ----
__launch_bounds__(256, 4)
__global__ void vq_mfma_kernel(const float* __restrict__ x,
                               const unsigned short* __restrict__ bs,
                               const float* __restrict__ esq,
                               const float* __restrict__ emb,
                               float* __restrict__ out) {
    const int tid  = threadIdx.x;
    const int lane = tid & 63;
    const int wv   = __builtin_amdgcn_readfirstlane(tid >> 6);  // 0..3
    const int n16  = lane & 15;   // m for A, n for B, col for D
    const int quad = lane >> 4;   // k-quad for A/B, row-quad for D

    const int g0 = blockIdx.x << 7;   // 128 positions per block
    const int b  = g0 >> 12;          // 128 | 4096: no b straddle
    const int n0 = g0 & 4095;

    __shared__ unsigned short lds_b[2][KT_USH];   // 2 x 6144 B tile buffers
    __shared__ int bk_s[PT];

    const char* bsb = (const char*)bs;
    char* l0 = (char*)&lds_b[0][0];
    char* l1 = (char*)&lds_b[1][0];

    // ---- issue kt0 tile staging first; latency hides under split3 ----
    // chunk c = fragment c (1024 B, linear lane*16): wv0->{0,4} wv1->{1,5}
    // wv2->{2} wv3->{3}  (wave-uniform branch)
    gload_lds16(bsb + wv * 1024 + lane * 16, l0 + wv * 1024);
    if (wv < 2)
        gload_lds16(bsb + (wv + 4) * 1024 + lane * 16, l0 + (wv + 4) * 1024);
    float eqf = esq[n16];   // kt0 |e|^2 for this lane's code column

    // ---- A fragments: load x, split to 3 bf16 frags (held whole kernel) ----
    // pos = g0 + wv*32 + mt*16 + n16 ; k(c) = ch*32 + quad*8 + j
    short8 ah[2][2], am[2][2], al[2][2];
    {
        const float* xb = x + (size_t)b * (CD * HWD) + n0 + wv * 32 + n16;
        #pragma unroll
        for (int mt = 0; mt < 2; ++mt)
            #pragma unroll
            for (int ch = 0; ch < 2; ++ch) {
                #pragma unroll
                for (int j = 0; j < 8; ++j) {
                    float v = xb[(size_t)(ch * 32 + quad * 8 + j) * HWD + mt * 16];
                    unsigned short h, m, l;
                    split3(v, h, m, l);
                    ah[mt][ch][j] = (short)h;
                    am[mt][ch][j] = (short)m;
                    al[mt][ch][j] = (short)l;
                }
            }
    }

    float bestd[8]; int bestk[8];
    #pragma unroll
    for (int i = 0; i < 8; ++i) { bestd[i] = FLT_MAX; bestk[i] = 0; }

    __syncthreads();   // kt0 tile resident (barrier drains vmcnt)

    // 6-class small->large accumulation; mt-inner gives 2-way MFMA ILP.
    // F[0],F[1]=e_h  F[2],F[3]=e_m  F[4],F[5]=e_l  (ch 0/1 each)
    #define CLUSTER(F, ACC)                                                   \
        { _Pragma("unroll")                                                   \
          for (int mt = 0; mt < 2; ++mt) ACC[mt] = MFMA(al[mt][0], F[0], ACC[mt]); \
          _Pragma("unroll")                                                   \
          for (int mt = 0; mt < 2; ++mt) ACC[mt] = MFMA(al[mt][1], F[1], ACC[mt]); \
          _Pragma("unroll")                                                   \
          for (int mt = 0; mt < 2; ++mt) ACC[mt] = MFMA(am[mt][0], F[2], ACC[mt]); \
          _Pragma("unroll")                                                   \
          for (int mt = 0; mt < 2; ++mt) ACC[mt] = MFMA(am[mt][1], F[3], ACC[mt]); \
          _Pragma("unroll")                                                   \
          for (int mt = 0; mt < 2; ++mt) ACC[mt] = MFMA(ah[mt][0], F[4], ACC[mt]); \
          _Pragma("unroll")                                                   \
          for (int mt = 0; mt < 2; ++mt) ACC[mt] = MFMA(ah[mt][1], F[5], ACC[mt]); \
          _Pragma("unroll")                                                   \
          for (int mt = 0; mt < 2; ++mt) ACC[mt] = MFMA(am[mt][0], F[0], ACC[mt]); \
          _Pragma("unroll")                                                   \
          for (int mt = 0; mt < 2; ++mt) ACC[mt] = MFMA(am[mt][1], F[1], ACC[mt]); \
          _Pragma("unroll")                                                   \
          for (int mt = 0; mt < 2; ++mt) ACC[mt] = MFMA(ah[mt][0], F[2], ACC[mt]); \
          _Pragma("unroll")                                                   \
          for (int mt = 0; mt < 2; ++mt) ACC[mt] = MFMA(ah[mt][1], F[3], ACC[mt]); \
          _Pragma("unroll")                                                   \
          for (int mt = 0; mt < 2; ++mt) ACC[mt] = MFMA(ah[mt][0], F[0], ACC[mt]); \
          _Pragma("unroll")                                                   \
          for (int mt = 0; mt < 2; ++mt) ACC[mt] = MFMA(ah[mt][1], F[1], ACC[mt]); }

    // distances + running argmin (k ascending: strict < keeps lowest k)
    #define TAIL(ACC, EQ, KV)                                                 \
        { _Pragma("unroll")                                                   \
          for (int mt = 0; mt < 2; ++mt)                                      \
              _Pragma("unroll")                                               \
              for (int r = 0; r < 4; ++r) {                                   \
                  float d = fmaf(-2.f, ACC[mt][r], (EQ));                     \
                  int idx = mt * 4 + r;                                       \
                  if (d < bestd[idx]) { bestd[idx] = d; bestk[idx] = (KV); }  \
              } }

    // ---- main loop: 16 iters x 2 kt; buffers alternate (static indexing) ----
    #pragma unroll 1
    for (int it = 0; it < 16; ++it) {
        const int kt0 = 2 * it;
        // even kt0: buf0 ready; stage kt0+1 -> buf1
        {
            const char* nb = bsb + (size_t)(kt0 + 1) * TILE_B;
            gload_lds16(nb + wv * 1024 + lane * 16, l1 + wv * 1024);
            if (wv < 2)
                gload_lds16(nb + (wv + 4) * 1024 + lane * 16, l1 + (wv + 4) * 1024);
            float eqn = esq[(kt0 + 1) * 16 + n16];
            short8 f[6];
            #pragma unroll
            for (int i = 0; i < 6; ++i)
                f[i] = *(const short8*)(l0 + i * 1024 + lane * 16);
            floatx4 acc[2];
            #pragma unroll
            for (int mt = 0; mt < 2; ++mt) acc[mt] = (floatx4){0.f, 0.f, 0.f, 0.f};
            CLUSTER(f, acc)
            TAIL(acc, eqf, kt0 * 16 + n16)
            eqf = eqn;
            __syncthreads();   // kt0+1 tile resident; buf0 readers done
        }
        // odd kt0+1: buf1 ready; stage kt0+2 -> buf0
        // (it=15 stages tile 32 / reads esq[512+n16] -> dedicated ws pads,
        //  values never consumed)
        {
            const char* nb = bsb + (size_t)(kt0 + 2) * TILE_B;
            gload_lds16(nb + wv * 1024 + lane * 16, l0 + wv * 1024);
            if (wv < 2)
                gload_lds16(nb + (wv + 4) * 1024 + lane * 16, l0 + (wv + 4) * 1024);
            float eqn = esq[(kt0 + 2) * 16 + n16];
            short8 f[6];
            #pragma unroll
            for (int i = 0; i < 6; ++i)
                f[i] = *(const short8*)(l1 + i * 1024 + lane * 16);
            floatx4 acc[2];
            #pragma unroll
            for (int mt = 0; mt < 2; ++mt) acc[mt] = (floatx4){0.f, 0.f, 0.f, 0.f};
            CLUSTER(f, acc)
            TAIL(acc, eqf, (kt0 + 1) * 16 + n16)
            eqf = eqn;
            __syncthreads();
        }
    }
    #undef CLUSTER
    #undef TAIL

    // ---- cross-lane argmin over the 16 code-columns (lane bits 0..3) ----
    #pragma unroll
    for (int msk = 1; msk <= 8; msk <<= 1)
        #pragma unroll
        for (int i = 0; i < 8; ++i) {
            float od = __shfl_xor(bestd[i], msk, 64);
            int   ok = __shfl_xor(bestk[i], msk, 64);
            bool take = (od < bestd[i]) || (od == bestd[i] && ok < bestk[i]);
            if (take) { bestd[i] = od; bestk[i] = ok; }
        }
    // D row = quad*4 + r within tile -> pos = wv*32 + mt*16 + quad*4 + r
    if (n16 == 0) {
        #pragma unroll
        for (int mt = 0; mt < 2; ++mt)
            #pragma unroll
            for (int r = 0; r < 4; ++r)
                bk_s[wv * 32 + mt * 16 + quad * 4 + r] = bestk[mt * 4 + r];
    }
    __syncthreads();

    // ---- gather epilogue: wave-uniform rows, 256-B coalesced, batched ----
    const size_t ob = (size_t)g0 * CD;
    for (int it = 0; it < 8; ++it) {
        float v[4]; int pp[4];
        #pragma unroll
        for (int j = 0; j < 4; ++j) {
            int p = (it * 4 + j) * 4 + wv;
            pp[j] = p;
            v[j]  = emb[bk_s[p] * CD + lane];   // L2-hot fp32 row
        }
        #pragma unroll
        for (int j = 0; j < 4; ++j)
            out[ob + (size_t)pp[j] * CD + lane] = v[j];
    }
}

// ---- fallback (no workspace): verbatim R7 kernel, 123.7 us known-good ----
__launch_bounds__(256, 2)
__global__ void vq_mfma_fb(const float* __restrict__ x,
                           const float* __restrict__ emb,
                           float* __restrict__ out) {
    const int tid  = threadIdx.x;
    const int lane = tid & 63;
    const int wv   = __builtin_amdgcn_readfirstlane(tid >> 6);  // 0..3
    const int n16  = lane & 15;
    const int quad = lane >> 4;

    const int g0 = blockIdx.x << 8;
    const int b  = g0 >> 12;
    const int n0 = g0 & 4095;

    __shared__ unsigned short es_h[KT][ESR];
    __shared__ unsigned short es_m[KT][ESR];
    __shared__ unsigned short es_l[KT][ESR];
    __shared__ float esq_p[2 * KT];
    __shared__ int   bk_s[256];

    short8 ah[4][2], am[4][2], al[4][2];
    {
        const float* xb = x + (size_t)b * (CD * HWD) + n0 + wv * 64 + n16;
        #pragma unroll
        for (int mt = 0; mt < 4; ++mt)
            #pragma unroll
            for (int ch = 0; ch < 2; ++ch) {
                #pragma unroll
                for (int j = 0; j < 8; ++j) {
                    float v = xb[(size_t)(ch * 32 + quad * 8 + j) * HWD + mt * 16];
                    unsigned short h, m, l;
                    split3(v, h, m, l);
                    ah[mt][ch][j] = (short)h;
                    am[mt][ch][j] = (short)m;
                    al[mt][ch][j] = (short)l;
                }
            }
    }

    float bestd[16]; int bestk[16];
    #pragma unroll
    for (int i = 0; i < 16; ++i) { bestd[i] = FLT_MAX; bestk[i] = 0; }

    const int lr   = tid >> 1;
    const int half = tid & 1;

    for (int nt = 0; nt < KD / KT; ++nt) {
        __syncthreads();
        {
            const float* eg = emb + (size_t)(nt * KT + lr) * CD + half * 32;
            float s = 0.f;
            #pragma unroll
            for (int q = 0; q < 8; ++q) {
                float4 ev = *(const float4*)(eg + q * 4);
                float vv[4] = {ev.x, ev.y, ev.z, ev.w};
                ushort4 h4, m4, l4;
                unsigned short* hp = (unsigned short*)&h4;
                unsigned short* mp = (unsigned short*)&m4;
                unsigned short* lp = (unsigned short*)&l4;
                #pragma unroll
                for (int i = 0; i < 4; ++i) {
                    s = fmaf(vv[i], vv[i], s);
                    split3(vv[i], hp[i], mp[i], lp[i]);
                }
                int c0 = half * 32 + q * 4;
                *(ushort4*)&es_h[lr][c0] = h4;
                *(ushort4*)&es_m[lr][c0] = m4;
                *(ushort4*)&es_l[lr][c0] = l4;
            }
            esq_p[2 * lr + half] = s;
        }
        __syncthreads();

        #pragma unroll 2
        for (int ln = 0; ln < 8; ++ln) {
            const int krow = ln * 16 + n16;
            const unsigned short* ph = &es_h[krow][quad * 8];
            const unsigned short* pm = &es_m[krow][quad * 8];
            const unsigned short* pl = &es_l[krow][quad * 8];
            short8 bh0 = *(const short8*)ph,  bh1 = *(const short8*)(ph + 32);
            short8 bm0 = *(const short8*)pm,  bm1 = *(const short8*)(pm + 32);
            short8 bl0 = *(const short8*)pl,  bl1 = *(const short8*)(pl + 32);
            const float eq = esq_p[2 * krow] + esq_p[2 * krow + 1];
            const int   kv = nt * KT + ln * 16 + n16;

            floatx4 acc[4];
            #pragma unroll
            for (int mt = 0; mt < 4; ++mt) acc[mt] = (floatx4){0.f, 0.f, 0.f, 0.f};

            #define STEPF(AR, B0, B1)                                         \
                { _Pragma("unroll")                                           \
                  for (int mt = 0; mt < 4; ++mt) acc[mt] = MFMA(AR[mt][0], B0, acc[mt]); \
                  _Pragma("unroll")                                           \
                  for (int mt = 0; mt < 4; ++mt) acc[mt] = MFMA(AR[mt][1], B1, acc[mt]); }
            STEPF(al, bh0, bh1)
            STEPF(am, bm0, bm1)
            STEPF(ah, bl0, bl1)
            STEPF(am, bh0, bh1)
            STEPF(ah, bm0, bm1)
            STEPF(ah, bh0, bh1)
            #undef STEPF

            #pragma unroll
            for (int mt = 0; mt < 4; ++mt)
                #pragma unroll
                for (int r = 0; r < 4; ++r) {
                    float d = fmaf(-2.f, acc[mt][r], eq);
                    int idx = mt * 4 + r;
                    if (d < bestd[idx]) { bestd[idx] = d; bestk[idx] = kv; }
                }
        }
    }

    #pragma unroll
    for (int msk = 1; msk <= 8; msk <<= 1)
        #pragma unroll
        for (int i = 0; i < 16; ++i) {
            float od = __shfl_xor(bestd[i], msk, 64);
            int   ok = __shfl_xor(bestk[i], msk, 64);
            bool take = (od < bestd[i]) || (od == bestd[i] && ok < bestk[i]);
            if (take) { bestd[i] = od; bestk[i] = ok; }
        }
    if (n16 == 0) {
        #pragma unroll
        for (int mt = 0; mt < 4; ++mt)
            #pragma unroll
            for (int r = 0; r < 4; ++r)
                bk_s[wv * 64 + mt * 16 + quad * 4 + r] = bestk[mt * 4 + r];
    }
    __syncthreads();

    const size_t ob = (size_t)g0 * CD;
    for (int it = 0; it < 16; ++it) {
        float v[4]; int pp[4];
        #pragma unroll
        for (int j = 0; j < 4; ++j) {
            int p = (it * 4 + j) * 4 + wv;
            pp[j] = p;
            v[j]  = emb[bk_s[p] * CD + lane];
        }
        #pragma unroll
        for (int j = 0; j < 4; ++j)
            out[ob + (size_t)pp[j] * CD + lane] = v[j];
    }
}

extern "C" void kernel_launch(void* const* d_in, const int* in_sizes, int n_in,
                              void* d_out, int out_size, void* d_ws, size_t ws_size,
                              hipStream_t stream) {
    const float* x   = (const float*)d_in[0];   // 32*64*64*64
    const float* emb = (const float*)d_in[1];   // 512*64
    float* out = (float*)d_out;                 // 8388608 floats

    if (d_ws != nullptr && ws_size >= (size_t)WS_NEEDED) {
        unsigned short* bs = (unsigned short*)d_ws;     // 196608 B + 6 KB pad
        float* esq = (float*)((char*)d_ws + ESQ_OFF);   // 512 + 32 pad floats
        vq_prep<<<16, 64, 0, stream>>>(emb, bs, esq);
        vq_mfma_kernel<<<1024, 256, 0, stream>>>(x, bs, esq, emb, out);
    } else {
        vq_mfma_fb<<<512, 256, 0, stream>>>(x, emb, out);
    }
}